// Round 9
// baseline (135.513 us; speedup 1.0000x reference)
//
#include <hip/hip_runtime.h>
#include <math.h>

// YOLOv1 loss: S=7, B=2, C=1, BATCH=32768
// predictions: (BATCH, 7, 7, 11) fp32   targets: (BATCH, 7, 7, 6) fp32
// out: 5 fp32 scalars: total, coord/bs, conf_obj/bs, conf_noobj/bs, class/bs
//
// R9: register streaming, 4 cells/thread as two R4-style pairs (lane stride
// 44 B, overlapping dword-aligned float4 @ +0/+4/+7 — the layout measured NOT
// to over-fetch). All 20 loads issued up-front (~20 KB in flight per wave) to
// keep HBM saturated through compute; block reduce amortized over 1024 cells.
// 1568 blocks. Stage-2: one block reduces 1568 float4 partials.

#define PRED_C 11
#define TGT_C  6
#define TPB    256
#define CELLS_PER_BLOCK 1024          // 256 threads x 4 cells
#define LAMBDA_COORD 5.0f
#define LAMBDA_NOOBJ 0.5f
#define EPSV 1e-6f

// dword-aligned vector loads (gfx950 global loads need only 4B alignment)
typedef float f4u __attribute__((ext_vector_type(4), aligned(4)));
typedef float f2u __attribute__((ext_vector_type(2), aligned(4)));

// fast sigmoid: |rel err| ~1e-6, far inside the 1.98 absmax budget
__device__ __forceinline__ float fsig(float x) {
    return __builtin_amdgcn_rcpf(1.0f + __expf(-x));
}

// a = p[0..3], b = p[4..7], c = p[7..10], t4 = t[0..3], t2 = t[4..5]
__device__ __forceinline__ void cell_loss(f4u a, f4u b, f4u c, f4u t4, f2u t2,
                                          float& acc_coord, float& acc_cobj,
                                          float& acc_cnoobj, float& acc_cls)
{
    const float tx = t4.x, ty = t4.y, tw = t4.z, th = t4.w;
    const float tconf = t2.x, tcls = t2.y;
    const float obj   = (tconf == 1.0f) ? 1.0f : 0.0f;
    const float noobj = (tconf == 0.0f) ? 1.0f : 0.0f;

    const float t1x = tx - tw * 0.5f, t1y = ty - th * 0.5f;
    const float t2x = tx + tw * 0.5f, t2y = ty + th * 0.5f;
    const float tarea = tw * th;

    // box0: x=a.x y=a.y w=a.z h=a.w conf=b.x
    // box1: x=b.y y=b.z w=b.w h=c.y conf=c.z   class=c.w
    const float px[2] = { a.x, b.y };
    const float py[2] = { a.y, b.z };
    const float pw[2] = { a.z, b.w };
    const float ph[2] = { a.w, c.y };
    const float pf[2] = { b.x, c.z };

    float iou[2], sx[2], sy[2], aw[2], ah[2], scf[2];
    #pragma unroll
    for (int bb = 0; bb < 2; ++bb) {
        sx[bb]  = fsig(px[bb]);
        sy[bb]  = fsig(py[bb]);
        scf[bb] = fsig(pf[bb]);
        aw[bb]  = fabsf(pw[bb]);
        ah[bb]  = fabsf(ph[bb]);
        const float p1x = sx[bb] - aw[bb] * 0.5f, p1y = sy[bb] - ah[bb] * 0.5f;
        const float p2x = sx[bb] + aw[bb] * 0.5f, p2y = sy[bb] + ah[bb] * 0.5f;
        const float ix = fminf(p2x, t2x) - fmaxf(p1x, t1x);
        const float iy = fminf(p2y, t2y) - fmaxf(p1y, t1y);
        const float inter = fmaxf(ix, 0.0f) * fmaxf(iy, 0.0f);
        const float parea = aw[bb] * ah[bb];
        iou[bb] = inter * __builtin_amdgcn_rcpf(parea + tarea - inter + EPSV);
    }
    // jnp.argmax: first occurrence of max -> box1 only if strictly greater
    const int best = (iou[1] > iou[0]) ? 1 : 0;

    const float dx = sx[best] - tx;
    const float dy = sy[best] - ty;
    const float dw = __builtin_amdgcn_sqrtf(aw[best] + EPSV) -
                     __builtin_amdgcn_sqrtf(tw + EPSV);
    const float dh = __builtin_amdgcn_sqrtf(ah[best] + EPSV) -
                     __builtin_amdgcn_sqrtf(th + EPSV);
    acc_coord += LAMBDA_COORD * obj * ((dx * dx + dy * dy) + (dw * dw + dh * dh));

    const float sc = scf[best];
    acc_cobj += obj * (sc - tconf) * (sc - tconf);

    const float d0 = scf[0] - tconf;
    const float d1 = scf[1] - tconf;
    acc_cnoobj += LAMBDA_NOOBJ * noobj * (d0 * d0 + d1 * d1);

    const float pc = c.w;
    const float bce = fmaxf(pc, 0.0f) - pc * tcls +
                      __logf(1.0f + __expf(-fabsf(pc)));
    acc_cls += obj * bce;
}

__global__ __launch_bounds__(TPB) void yolo_partial_kernel(
    const float* __restrict__ pred,
    const float* __restrict__ tgt,
    float* __restrict__ partials)   // gridDim.x float4s
{
    __shared__ float red[4][4];
    const int tid = threadIdx.x;
    const long long base = (long long)blockIdx.x * CELLS_PER_BLOCK;

    // four cells: two lane-contiguous pairs
    const long long cA0 = base + tid;          // pair A
    const long long cA1 = cA0 + TPB;
    const long long cB0 = base + 512 + tid;    // pair B
    const long long cB1 = cB0 + TPB;

    const float* pA0 = pred + cA0 * PRED_C;
    const float* pA1 = pred + cA1 * PRED_C;
    const float* pB0 = pred + cB0 * PRED_C;
    const float* pB1 = pred + cB1 * PRED_C;
    const float* tA0 = tgt + cA0 * TGT_C;
    const float* tA1 = tgt + cA1 * TGT_C;
    const float* tB0 = tgt + cB0 * TGT_C;
    const float* tB1 = tgt + cB1 * TGT_C;

    // ---- issue ALL 20 loads up front (deep MLP, ~20 KB in flight per wave)
    const f4u aA0 = *(const f4u*)(pA0);
    const f4u bA0 = *(const f4u*)(pA0 + 4);
    const f4u cA0v = *(const f4u*)(pA0 + 7);
    const f4u aA1 = *(const f4u*)(pA1);
    const f4u bA1 = *(const f4u*)(pA1 + 4);
    const f4u cA1v = *(const f4u*)(pA1 + 7);
    const f4u aB0 = *(const f4u*)(pB0);
    const f4u bB0 = *(const f4u*)(pB0 + 4);
    const f4u cB0v = *(const f4u*)(pB0 + 7);
    const f4u aB1 = *(const f4u*)(pB1);
    const f4u bB1 = *(const f4u*)(pB1 + 4);
    const f4u cB1v = *(const f4u*)(pB1 + 7);
    const f4u t4A0 = *(const f4u*)(tA0);
    const f2u t2A0 = *(const f2u*)(tA0 + 4);
    const f4u t4A1 = *(const f4u*)(tA1);
    const f2u t2A1 = *(const f2u*)(tA1 + 4);
    const f4u t4B0 = *(const f4u*)(tB0);
    const f2u t2B0 = *(const f2u*)(tB0 + 4);
    const f4u t4B1 = *(const f4u*)(tB1);
    const f2u t2B1 = *(const f2u*)(tB1 + 4);

    float coord = 0.f, cobj = 0.f, cnoobj = 0.f, cls = 0.f;
    cell_loss(aA0, bA0, cA0v, t4A0, t2A0, coord, cobj, cnoobj, cls);
    cell_loss(aA1, bA1, cA1v, t4A1, t2A1, coord, cobj, cnoobj, cls);
    cell_loss(aB0, bB0, cB0v, t4B0, t2B0, coord, cobj, cnoobj, cls);
    cell_loss(aB1, bB1, cB1v, t4B1, t2B1, coord, cobj, cnoobj, cls);

    // ---- reduction: wave shuffle (64-wide) -> cross-wave LDS -> float4 store
    #pragma unroll
    for (int off = 32; off >= 1; off >>= 1) {
        coord  += __shfl_down(coord, off);
        cobj   += __shfl_down(cobj, off);
        cnoobj += __shfl_down(cnoobj, off);
        cls    += __shfl_down(cls, off);
    }
    const int wave = tid >> 6;
    const int lane = tid & 63;
    if (lane == 0) {
        red[wave][0] = coord;
        red[wave][1] = cobj;
        red[wave][2] = cnoobj;
        red[wave][3] = cls;
    }
    __syncthreads();
    if (tid == 0) {
        float4 v;
        v.x = red[0][0] + red[1][0] + red[2][0] + red[3][0];
        v.y = red[0][1] + red[1][1] + red[2][1] + red[3][1];
        v.z = red[0][2] + red[1][2] + red[2][2] + red[3][2];
        v.w = red[0][3] + red[1][3] + red[2][3] + red[3][3];
        ((float4*)partials)[blockIdx.x] = v;
    }
}

__global__ __launch_bounds__(1024) void yolo_final_kernel(
    const float* __restrict__ partials,
    float* __restrict__ out,
    int nblk,
    float inv_bs)
{
    __shared__ float red[16][4];
    const int tid = threadIdx.x;

    float c = 0.f, co = 0.f, cn = 0.f, cl = 0.f;
    for (int i = tid; i < nblk; i += 1024) {
        const float4 v = ((const float4*)partials)[i];
        c += v.x; co += v.y; cn += v.z; cl += v.w;
    }
    #pragma unroll
    for (int off = 32; off >= 1; off >>= 1) {
        c  += __shfl_down(c, off);
        co += __shfl_down(co, off);
        cn += __shfl_down(cn, off);
        cl += __shfl_down(cl, off);
    }
    const int wave = tid >> 6;
    const int lane = tid & 63;
    if (lane == 0) {
        red[wave][0] = c;
        red[wave][1] = co;
        red[wave][2] = cn;
        red[wave][3] = cl;
    }
    __syncthreads();
    if (tid == 0) {
        float sc = 0.f, sco = 0.f, scn = 0.f, scl = 0.f;
        #pragma unroll
        for (int w = 0; w < 16; ++w) {
            sc  += red[w][0];
            sco += red[w][1];
            scn += red[w][2];
            scl += red[w][3];
        }
        out[0] = (sc + sco + scn + scl) * inv_bs;
        out[1] = sc  * inv_bs;
        out[2] = sco * inv_bs;
        out[3] = scn * inv_bs;
        out[4] = scl * inv_bs;
    }
}

extern "C" void kernel_launch(void* const* d_in, const int* in_sizes, int n_in,
                              void* d_out, int out_size, void* d_ws, size_t ws_size,
                              hipStream_t stream) {
    const float* pred = (const float*)d_in[0];
    const float* tgt  = (const float*)d_in[1];
    float* out = (float*)d_out;
    float* partials = (float*)d_ws;

    const long long batch = (long long)in_sizes[0] / (7 * 7 * PRED_C);
    const long long cells = batch * 49;                 // 1,605,632
    const int nblk = (int)(cells / CELLS_PER_BLOCK);    // 1568 exact

    yolo_partial_kernel<<<nblk, TPB, 0, stream>>>(pred, tgt, partials);
    yolo_final_kernel<<<1, 1024, 0, stream>>>(partials, out, nblk,
                                              1.0f / (float)batch);
}